// Round 1
// baseline (115.911 us; speedup 1.0000x reference)
//
#include <hip/hip_runtime.h>

#define B_ 2
#define C_ 4
#define H_ 512
#define W_ 512
#define V_ 100000
#define F_ 200000
#define A_ 8

#define NPIX (B_ * C_ * H_ * W_)   // 2,097,152

// ---------------------------------------------------------------------------
// Kernel 1: face normals.  face_normal[b][f] = cross(v1-v0, v2-v0)
// ---------------------------------------------------------------------------
__global__ void k_face_normal(const float* __restrict__ vertex_pos,
                              const int* __restrict__ faces,
                              float* __restrict__ face_normal) {
    int t = blockIdx.x * blockDim.x + threadIdx.x;
    if (t >= B_ * F_) return;
    int b = t / F_;
    int f = t - b * F_;
    int i0 = faces[f * 3 + 0];
    int i1 = faces[f * 3 + 1];
    int i2 = faces[f * 3 + 2];
    const float* vp = vertex_pos + (size_t)b * V_ * 3;
    float p0x = vp[i0 * 3 + 0], p0y = vp[i0 * 3 + 1], p0z = vp[i0 * 3 + 2];
    float p1x = vp[i1 * 3 + 0], p1y = vp[i1 * 3 + 1], p1z = vp[i1 * 3 + 2];
    float p2x = vp[i2 * 3 + 0], p2y = vp[i2 * 3 + 1], p2z = vp[i2 * 3 + 2];
    float e1x = p1x - p0x, e1y = p1y - p0y, e1z = p1z - p0z;
    float e2x = p2x - p0x, e2y = p2y - p0y, e2z = p2z - p0z;
    float nx = e1y * e2z - e1z * e2y;
    float ny = e1z * e2x - e1x * e2z;
    float nz = e1x * e2y - e1y * e2x;
    face_normal[(size_t)t * 3 + 0] = nx;
    face_normal[(size_t)t * 3 + 1] = ny;
    face_normal[(size_t)t * 3 + 2] = nz;
}

// ---------------------------------------------------------------------------
// Kernel 2: vertex normals.  vn[b][v] = sum_a w[v][a] * fn[b][adj[v][a]]
// ---------------------------------------------------------------------------
__global__ void k_vertex_normal(const float* __restrict__ face_normal,
                                const int* __restrict__ vert_adj_faces,
                                const float* __restrict__ vert_adj_weights,
                                float* __restrict__ vertex_normal) {
    int t = blockIdx.x * blockDim.x + threadIdx.x;
    if (t >= B_ * V_) return;
    int b = t / V_;
    int v = t - b * V_;
    const int* adj = vert_adj_faces + (size_t)v * A_;
    const float* wt = vert_adj_weights + (size_t)v * A_;
    const float* fn = face_normal + (size_t)b * F_ * 3;
    float ax = 0.f, ay = 0.f, az = 0.f;
#pragma unroll
    for (int a = 0; a < A_; ++a) {
        int f = adj[a];
        float w = wt[a];
        ax += w * fn[(size_t)f * 3 + 0];
        ay += w * fn[(size_t)f * 3 + 1];
        az += w * fn[(size_t)f * 3 + 2];
    }
    vertex_normal[(size_t)t * 3 + 0] = ax;
    vertex_normal[(size_t)t * 3 + 1] = ay;
    vertex_normal[(size_t)t * 3 + 2] = az;
}

// ---------------------------------------------------------------------------
// Kernel 3: projection.  iv[b][c][v] = persp(K * (E * homo(pos)))
// ---------------------------------------------------------------------------
__global__ void k_project(const float* __restrict__ vertex_pos,
                          const float* __restrict__ intrinsics,
                          const float* __restrict__ extrinsics,
                          float* __restrict__ iv) {
    int t = blockIdx.x * blockDim.x + threadIdx.x;
    if (t >= B_ * C_ * V_) return;
    int v = t % V_;
    int bc = t / V_;          // b*C + c
    int b = bc / C_;
    const float* vp = vertex_pos + ((size_t)b * V_ + v) * 3;
    float x = vp[0], y = vp[1], z = vp[2];
    const float* E = extrinsics + (size_t)bc * 12;   // 3x4 row-major
    float cv0 = x * E[0] + y * E[1] + z * E[2]  + E[3];
    float cv1 = x * E[4] + y * E[5] + z * E[6]  + E[7];
    float cv2 = x * E[8] + y * E[9] + z * E[10] + E[11];
    const float* K = intrinsics + (size_t)bc * 9;    // 3x3 row-major
    float i0 = cv0 * K[0] + cv1 * K[1] + cv2 * K[2];
    float i1 = cv0 * K[3] + cv1 * K[4] + cv2 * K[5];
    float i2 = cv0 * K[6] + cv1 * K[7] + cv2 * K[8];
    float* o = iv + (size_t)t * 3;
    o[0] = i0 / i2;
    o[1] = i1 / i2;
    o[2] = i2;
}

// ---------------------------------------------------------------------------
// Kernel 4: per-pixel shading + 5 output images
// out shape: [5][B][C][H][W][3]
// ---------------------------------------------------------------------------
__global__ void k_pixel(const float* __restrict__ vertex_pos,
                        const int* __restrict__ faces,
                        const float* __restrict__ inverse_extrinsics,
                        const int* __restrict__ face_id,
                        const float* __restrict__ bary,
                        const float* __restrict__ vertex_normal,
                        const float* __restrict__ iv,
                        float* __restrict__ out) {
    int p = blockIdx.x * blockDim.x + threadIdx.x;
    if (p >= NPIX) return;
    int bc = p / (H_ * W_);   // b*C + c
    int b = bc / C_;
    int fid = face_id[p];

    float fg = 0.f;
    float px = 0.f, py = 0.f, pz = 0.f;
    float nx = 0.f, ny = 0.f, nz = 0.f;
    float dd = 0.f;
    float sx = 0.f, sy = 0.f, sz = 0.f;

    if (fid >= 0) {
        int i0 = faces[fid * 3 + 0];
        int i1 = faces[fid * 3 + 1];
        int i2 = faces[fid * 3 + 2];
        float w0 = bary[(size_t)p * 3 + 0];
        float w1 = bary[(size_t)p * 3 + 1];
        float w2 = bary[(size_t)p * 3 + 2];
        const float* vp = vertex_pos    + (size_t)b  * V_ * 3;
        const float* vn = vertex_normal + (size_t)b  * V_ * 3;
        const float* sv = iv            + (size_t)bc * V_ * 3;

        px = w0 * vp[i0 * 3 + 0] + w1 * vp[i1 * 3 + 0] + w2 * vp[i2 * 3 + 0];
        py = w0 * vp[i0 * 3 + 1] + w1 * vp[i1 * 3 + 1] + w2 * vp[i2 * 3 + 1];
        pz = w0 * vp[i0 * 3 + 2] + w1 * vp[i1 * 3 + 2] + w2 * vp[i2 * 3 + 2];

        nx = w0 * vn[i0 * 3 + 0] + w1 * vn[i1 * 3 + 0] + w2 * vn[i2 * 3 + 0];
        ny = w0 * vn[i0 * 3 + 1] + w1 * vn[i1 * 3 + 1] + w2 * vn[i2 * 3 + 1];
        nz = w0 * vn[i0 * 3 + 2] + w1 * vn[i1 * 3 + 2] + w2 * vn[i2 * 3 + 2];

        sx = w0 * sv[i0 * 3 + 0] + w1 * sv[i1 * 3 + 0] + w2 * sv[i2 * 3 + 0];
        sy = w0 * sv[i0 * 3 + 1] + w1 * sv[i1 * 3 + 1] + w2 * sv[i2 * 3 + 1];
        sz = w0 * sv[i0 * 3 + 2] + w1 * sv[i1 * 3 + 2] + w2 * sv[i2 * 3 + 2];

        float nlen = sqrtf(nx * nx + ny * ny + nz * nz);
        nlen = fmaxf(nlen, 1e-12f);
        nx /= nlen; ny /= nlen; nz /= nlen;

        const float* ie = inverse_extrinsics + (size_t)bc * 16;  // 4x4 row-major
        float iw = ie[15];
        float ox = ie[3]  / iw;
        float oy = ie[7]  / iw;
        float oz = ie[11] / iw;
        float dx = ox - px, dy = oy - py, dz = oz - pz;
        dd = sqrtf(dx * dx + dy * dy + dz * dz);
        fg = 1.f;
    }

    const size_t PLANE = (size_t)NPIX * 3;
    size_t o = (size_t)p * 3;
    out[0 * PLANE + o + 0] = fg;
    out[0 * PLANE + o + 1] = fg;
    out[0 * PLANE + o + 2] = fg;
    out[1 * PLANE + o + 0] = px;
    out[1 * PLANE + o + 1] = py;
    out[1 * PLANE + o + 2] = pz;
    out[2 * PLANE + o + 0] = nx;
    out[2 * PLANE + o + 1] = ny;
    out[2 * PLANE + o + 2] = nz;
    out[3 * PLANE + o + 0] = dd;
    out[3 * PLANE + o + 1] = dd;
    out[3 * PLANE + o + 2] = dd;
    out[4 * PLANE + o + 0] = sx;
    out[4 * PLANE + o + 1] = sy;
    out[4 * PLANE + o + 2] = sz;
}

// ---------------------------------------------------------------------------
extern "C" void kernel_launch(void* const* d_in, const int* in_sizes, int n_in,
                              void* d_out, int out_size, void* d_ws, size_t ws_size,
                              hipStream_t stream) {
    const float* vertex_pos         = (const float*)d_in[0];
    const int*   faces              = (const int*)  d_in[1];
    const int*   vert_adj_faces     = (const int*)  d_in[2];
    const float* vert_adj_weights   = (const float*)d_in[3];
    const float* intrinsics         = (const float*)d_in[4];
    const float* extrinsics         = (const float*)d_in[5];
    const float* inverse_extrinsics = (const float*)d_in[6];
    const int*   face_id            = (const int*)  d_in[7];
    const float* barycentrics       = (const float*)d_in[8];
    float* out = (float*)d_out;

    // workspace layout (all 16B-aligned)
    char* ws = (char*)d_ws;
    float* face_normal   = (float*)(ws);                        // B*F*3 = 4.8 MB
    float* vertex_normal = (float*)(ws + 4800000);              // B*V*3 = 2.4 MB
    float* iv            = (float*)(ws + 7200000);              // B*C*V*3 = 9.6 MB

    const int TPB = 256;
    hipLaunchKernelGGL(k_face_normal, dim3((B_ * F_ + TPB - 1) / TPB), dim3(TPB), 0, stream,
                       vertex_pos, faces, face_normal);
    hipLaunchKernelGGL(k_vertex_normal, dim3((B_ * V_ + TPB - 1) / TPB), dim3(TPB), 0, stream,
                       face_normal, vert_adj_faces, vert_adj_weights, vertex_normal);
    hipLaunchKernelGGL(k_project, dim3((B_ * C_ * V_ + TPB - 1) / TPB), dim3(TPB), 0, stream,
                       vertex_pos, intrinsics, extrinsics, iv);
    hipLaunchKernelGGL(k_pixel, dim3((NPIX + TPB - 1) / TPB), dim3(TPB), 0, stream,
                       vertex_pos, faces, inverse_extrinsics, face_id, barycentrics,
                       vertex_normal, iv, out);
}